// Round 3
// baseline (5892.529 us; speedup 1.0000x reference)
//
#include <hip/hip_runtime.h>
#include <cstddef>

// Mamba2 forward, MI355X. Runtime input-dtype detection (bf16 vs fp32), then:
//  1 gemm_nt<...>   : zxbcdt = u @ W_in^T  (dual-dtype A/B loads, bf16 ws out)
//  2 conv_silu_k    : causal conv4 + SiLU
//  3 dt_softplus_k  : dt = softplus(raw + dt_bias)
//  4 chunk_states_k : per-chunk cum(dA), decay, states = B^T(decay*dt*x)
//  5 scan_k         : in-place inter-chunk state scan
//  6 scores_k       : scores = C.B^T per (b,chunk)   (head-independent, g=1)
//  7 ydiag_off_k    : Y = (scores*L)@xdt + exp(cum)*C@prev^T + D*x  -> zx dead cols
//  8 gatenorm_k     : yg = y*silu(z); RMSNorm (in-place)
//  9 gemm_nt<...>   : out = yn @ W_out^T  (store dtype per flag)

#define D_MODEL 2048
#define D_STATE 64
#define D_HEAD 128
#define CHUNK 256
#define D_INNER 4096
#define NHEADS 32
#define CONV_DIM 4224
#define D_IN_PROJ 8352
#define BATCH 2
#define SEQLEN 4096
#define NC 16
#define ROWS 8192
#define EPS_F 1e-5f

typedef unsigned short u16;

__device__ __forceinline__ float bf2f(u16 u) { return __uint_as_float(((unsigned)u) << 16); }
__device__ __forceinline__ u16 f2bf(float f) {
  unsigned x = __float_as_uint(f);
  x += 0x7FFFu + ((x >> 16) & 1u);
  return (u16)(x >> 16);
}

// ---------------- dtype detection ----------------
// bf16 W_in: exponent fields cluster ~[105,125] -> weird ~0.
// fp32-as-u16: even halves are mantissa bits (uniform) -> weird ~36% of 8192.
__global__ void detect_k(const u16* __restrict__ win, int* __restrict__ flag) {
  __shared__ int cnt;
  if (threadIdx.x == 0) cnt = 0;
  __syncthreads();
  int c = 0;
  for (int i = threadIdx.x; i < 8192; i += 256) {
    u16 x = win[i];
    int e = (x >> 7) & 0xFF;
    if (e != 0 && (e < 90 || e > 160)) c++;
  }
  atomicAdd(&cnt, c);
  __syncthreads();
  if (threadIdx.x == 0) *flag = (cnt > 512) ? 1 : 0;
}

// ---------------- convert small params to fp32 ws arrays ----------------
__device__ __forceinline__ float readin(const void* p, int i, int isf32) {
  return isf32 ? ((const float*)p)[i] : bf2f(((const u16*)p)[i]);
}
#define N_CW 16896
#define N_CB 4224
#define N_SMALL (N_CW + N_CB + 32 + 32 + 32 + 4096)
__global__ __launch_bounds__(256) void convert_small_k(const void* cw, const void* cb,
                                                       const void* dtb, const void* alog,
                                                       const void* Dv, const void* nw,
                                                       const int* __restrict__ flag,
                                                       float* __restrict__ dst) {
  int idx = blockIdx.x * 256 + threadIdx.x;
  if (idx >= N_SMALL) return;
  int f = *flag;
  float v; int o = idx;
  if (o < N_CW) { v = readin(cw, o, f); }
  else if ((o -= N_CW) < N_CB) { v = readin(cb, o, f); }
  else if ((o -= N_CB) < 32) { v = readin(dtb, o, f); }
  else if ((o -= 32) < 32) { v = readin(alog, o, f); }
  else if ((o -= 32) < 32) { v = readin(Dv, o, f); }
  else { o -= 32; v = readin(nw, o, f); }
  dst[idx] = v;
}

// ---------------- GEMM: C[M,N] = A[M,K](lda) * B[N,K]^T ----------------
// AF/BF: 0 = bf16 source, 1 = fp32 source. OF: 0 = bf16 store, 1 = fp32 store.
template <int AF, int BF, int OF>
__global__ __launch_bounds__(256) void gemm_nt(const void* __restrict__ Av, int lda,
                                               const void* __restrict__ Bv,
                                               void* __restrict__ Cv,
                                               int M, int N, int K,
                                               const int* __restrict__ flagp, int want) {
  if (*flagp != want) return;
  __shared__ __align__(16) float As[16][132];
  __shared__ __align__(16) float Bs[16][132];
  const int tid = threadIdx.x;
  const int bm = blockIdx.y << 7, bn = blockIdx.x << 7;
  const int tx = tid & 15, ty = tid >> 4;
  const int m0 = ty << 3, n0 = tx << 3;
  const int lr = tid >> 1;          // 0..127 tile row
  const int lk = (tid & 1) << 3;    // 0 or 8
  const bool bok = (bn + lr) < N;
  float acc[8][8];
  #pragma unroll
  for (int i = 0; i < 8; ++i)
    #pragma unroll
    for (int j = 0; j < 8; ++j) acc[i][j] = 0.f;
  for (int k0 = 0; k0 < K; k0 += 16) {
    float av[8], bv[8];
    if (AF) {
      const float* ap = (const float*)Av + (size_t)(bm + lr) * lda + lk + k0;
      float4 a0 = *(const float4*)ap, a1 = *(const float4*)(ap + 4);
      av[0]=a0.x; av[1]=a0.y; av[2]=a0.z; av[3]=a0.w;
      av[4]=a1.x; av[5]=a1.y; av[6]=a1.z; av[7]=a1.w;
    } else {
      const u16* ap = (const u16*)Av + (size_t)(bm + lr) * lda + lk + k0;
      ushort4 a0 = *(const ushort4*)ap, a1 = *(const ushort4*)(ap + 4);
      av[0]=bf2f(a0.x); av[1]=bf2f(a0.y); av[2]=bf2f(a0.z); av[3]=bf2f(a0.w);
      av[4]=bf2f(a1.x); av[5]=bf2f(a1.y); av[6]=bf2f(a1.z); av[7]=bf2f(a1.w);
    }
    if (bok) {
      if (BF) {
        const float* bp = (const float*)Bv + (size_t)(bn + lr) * K + lk + k0;
        float4 b0 = *(const float4*)bp, b1 = *(const float4*)(bp + 4);
        bv[0]=b0.x; bv[1]=b0.y; bv[2]=b0.z; bv[3]=b0.w;
        bv[4]=b1.x; bv[5]=b1.y; bv[6]=b1.z; bv[7]=b1.w;
      } else {
        const u16* bp = (const u16*)Bv + (size_t)(bn + lr) * K + lk + k0;
        ushort4 b0 = *(const ushort4*)bp, b1 = *(const ushort4*)(bp + 4);
        bv[0]=bf2f(b0.x); bv[1]=bf2f(b0.y); bv[2]=bf2f(b0.z); bv[3]=bf2f(b0.w);
        bv[4]=bf2f(b1.x); bv[5]=bf2f(b1.y); bv[6]=bf2f(b1.z); bv[7]=bf2f(b1.w);
      }
    } else {
      #pragma unroll
      for (int q = 0; q < 8; ++q) bv[q] = 0.f;
    }
    #pragma unroll
    for (int q = 0; q < 8; ++q) { As[lk + q][lr] = av[q]; Bs[lk + q][lr] = bv[q]; }
    __syncthreads();
    #pragma unroll
    for (int k = 0; k < 16; ++k) {
      float4 av0 = *(const float4*)&As[k][m0];
      float4 av1 = *(const float4*)&As[k][m0 + 4];
      float4 bv0 = *(const float4*)&Bs[k][n0];
      float4 bv1 = *(const float4*)&Bs[k][n0 + 4];
      float a[8] = {av0.x, av0.y, av0.z, av0.w, av1.x, av1.y, av1.z, av1.w};
      float bb[8] = {bv0.x, bv0.y, bv0.z, bv0.w, bv1.x, bv1.y, bv1.z, bv1.w};
      #pragma unroll
      for (int i = 0; i < 8; ++i)
        #pragma unroll
        for (int j = 0; j < 8; ++j) acc[i][j] += a[i] * bb[j];
    }
    __syncthreads();
  }
  #pragma unroll
  for (int i = 0; i < 8; ++i) {
    size_t crow = (size_t)(bm + m0 + i) * N;
    #pragma unroll
    for (int j = 0; j < 8; ++j) {
      int n = bn + n0 + j;
      if (n < N) {
        if (OF) ((float*)Cv)[crow + n] = acc[i][j];
        else    ((u16*)Cv)[crow + n] = f2bf(acc[i][j]);
      }
    }
  }
}

// ---------------- causal conv4 + SiLU ----------------
__global__ __launch_bounds__(256) void conv_silu_k(const u16* __restrict__ zx,
                                                   const float* __restrict__ cwf,
                                                   const float* __restrict__ cbf,
                                                   u16* __restrict__ xBC) {
  int c = blockIdx.x * 256 + threadIdx.x;
  if (c >= CONV_DIM) return;
  int row = blockIdx.y;
  int b = row >> 12, l = row & 4095;
  float acc = cbf[c];
  #pragma unroll
  for (int k = 0; k < 4; ++k) {
    int li = l - 3 + k;
    if (li >= 0)
      acc += bf2f(zx[(size_t)(b * SEQLEN + li) * D_IN_PROJ + D_INNER + c]) * cwf[c * 4 + k];
  }
  acc = acc / (1.f + __expf(-acc));
  xBC[(size_t)row * CONV_DIM + c] = f2bf(acc);
}

// ---------------- dt = softplus(raw + bias) ----------------
__global__ __launch_bounds__(256) void dt_softplus_k(const u16* __restrict__ zx,
                                                     const float* __restrict__ dtbf,
                                                     float* __restrict__ dtf) {
  int idx = blockIdx.x * 256 + threadIdx.x;   // ROWS*NHEADS
  int i = idx >> 5, h = idx & 31;
  float x = bf2f(zx[(size_t)i * D_IN_PROJ + (D_INNER + CONV_DIM) + h]) + dtbf[h];
  float sp = (x > 20.f) ? x : log1pf(__expf(fminf(x, 20.f)));
  dtf[idx] = sp;
}

// ---------------- per-chunk cum, decay, states ----------------
__global__ __launch_bounds__(256) void chunk_states_k(const u16* __restrict__ xBC,
                                                      const float* __restrict__ dtf,
                                                      const float* __restrict__ alogf,
                                                      float* __restrict__ cumf,
                                                      float* __restrict__ cdec,
                                                      float* __restrict__ states) {
  const int h = blockIdx.x, c = blockIdx.y, b = blockIdx.z;
  const int tid = threadIdx.x;
  __shared__ __align__(16) float dt_sh[CHUNK];
  __shared__ __align__(16) float cum_sh[CHUNK];
  __shared__ __align__(16) float w_sh[CHUNK];
  __shared__ __align__(16) float xs[64][132];
  __shared__ __align__(16) float Bst[64][68];
  const int rowbase = b * SEQLEN + c * CHUNK;
  dt_sh[tid] = dtf[(size_t)(rowbase + tid) * NHEADS + h];
  __syncthreads();
  if (tid == 0) {
    float Aneg = -__expf(alogf[h]);
    float s = 0.f;
    for (int z = 0; z < CHUNK; ++z) { s += dt_sh[z] * Aneg; cum_sh[z] = s; }
  }
  __syncthreads();
  float cl = cum_sh[CHUNK - 1];
  w_sh[tid] = __expf(fminf(cl - cum_sh[tid], 0.f)) * dt_sh[tid];
  cumf[((size_t)(b * NC + c) * NHEADS + h) * CHUNK + tid] = cum_sh[tid];
  if (tid == 0) cdec[(b * NC + c) * NHEADS + h] = __expf(fminf(cl, 0.f));
  __syncthreads();
  const int tx = tid & 15, ty = tid >> 4;
  const int p0 = tx << 3, n0 = ty << 2;
  float acc[8][4];
  #pragma unroll
  for (int i = 0; i < 8; ++i)
    #pragma unroll
    for (int j = 0; j < 4; ++j) acc[i][j] = 0.f;
  for (int z0 = 0; z0 < CHUNK; z0 += 64) {
    int zz = tid >> 2;
    int pq = (tid & 3) << 5;
    const u16* xp = xBC + (size_t)(rowbase + z0 + zz) * CONV_DIM + h * D_HEAD + pq;
    #pragma unroll
    for (int q = 0; q < 8; ++q) {
      ushort4 v = *(const ushort4*)(xp + q * 4);
      xs[zz][pq + q*4 + 0] = bf2f(v.x); xs[zz][pq + q*4 + 1] = bf2f(v.y);
      xs[zz][pq + q*4 + 2] = bf2f(v.z); xs[zz][pq + q*4 + 3] = bf2f(v.w);
    }
    int nq = (tid & 3) << 4;
    const u16* bpp = xBC + (size_t)(rowbase + z0 + zz) * CONV_DIM + D_INNER + nq;
    float wz = w_sh[z0 + zz];
    #pragma unroll
    for (int q = 0; q < 4; ++q) {
      ushort4 v = *(const ushort4*)(bpp + q * 4);
      Bst[zz][nq + q*4 + 0] = bf2f(v.x) * wz; Bst[zz][nq + q*4 + 1] = bf2f(v.y) * wz;
      Bst[zz][nq + q*4 + 2] = bf2f(v.z) * wz; Bst[zz][nq + q*4 + 3] = bf2f(v.w) * wz;
    }
    __syncthreads();
    #pragma unroll 4
    for (int z = 0; z < 64; ++z) {
      float4 x0 = *(const float4*)&xs[z][p0];
      float4 x1 = *(const float4*)&xs[z][p0 + 4];
      float4 bv = *(const float4*)&Bst[z][n0];
      float xv[8] = {x0.x, x0.y, x0.z, x0.w, x1.x, x1.y, x1.z, x1.w};
      float bb[4] = {bv.x, bv.y, bv.z, bv.w};
      #pragma unroll
      for (int i = 0; i < 8; ++i)
        #pragma unroll
        for (int j = 0; j < 4; ++j) acc[i][j] += xv[i] * bb[j];
    }
    __syncthreads();
  }
  float* sp = states + ((size_t)(b * NC + c) * NHEADS + h) * (D_HEAD * D_STATE);
  #pragma unroll
  for (int i = 0; i < 8; ++i)
    #pragma unroll
    for (int j = 0; j < 4; ++j)
      sp[(size_t)(p0 + i) * D_STATE + n0 + j] = acc[i][j];
}

// ---------------- inter-chunk scan (IN-PLACE: states -> prev_states) ----------------
__global__ __launch_bounds__(256) void scan_k(float* __restrict__ states,
                                              const float* __restrict__ cdec) {
  const int h = blockIdx.x, b = blockIdx.y;
  const int tid = threadIdx.x;
  float carry[32];
  #pragma unroll
  for (int j = 0; j < 32; ++j) carry[j] = 0.f;
  for (int c = 0; c < NC; ++c) {
    size_t base = ((size_t)(b * NC + c) * NHEADS + h) * (D_HEAD * D_STATE);
    float dec = cdec[(b * NC + c) * NHEADS + h];
    #pragma unroll
    for (int j = 0; j < 32; ++j) {
      size_t e = base + tid + j * 256;
      float s = states[e];
      states[e] = carry[j];            // prev_states for chunk c
      carry[j] = carry[j] * dec + s;
    }
  }
}

// ---------------- scores = C . B^T  (head-independent) ----------------
__global__ __launch_bounds__(256) void scores_k(const u16* __restrict__ xBC,
                                                float* __restrict__ scores) {
  const int bx = blockIdx.x;            // 0..15
  const int c = blockIdx.y, b = blockIdx.z;
  const int s0 = (bx >> 2) << 6, z0 = (bx & 3) << 6;
  __shared__ __align__(16) float Cs[64][68];   // [n][s]
  __shared__ __align__(16) float Bs[64][68];   // [n][z]
  const int tid = threadIdx.x;
  const int rowbase = b * SEQLEN + c * CHUNK;
  int r = tid >> 2, nq = (tid & 3) << 4;
  const u16* cp = xBC + (size_t)(rowbase + s0 + r) * CONV_DIM + D_INNER + D_STATE + nq;
  const u16* bp = xBC + (size_t)(rowbase + z0 + r) * CONV_DIM + D_INNER + nq;
  #pragma unroll
  for (int q = 0; q < 16; q += 4) {
    ushort4 v = *(const ushort4*)(cp + q);
    Cs[nq+q+0][r] = bf2f(v.x); Cs[nq+q+1][r] = bf2f(v.y);
    Cs[nq+q+2][r] = bf2f(v.z); Cs[nq+q+3][r] = bf2f(v.w);
    ushort4 w = *(const ushort4*)(bp + q);
    Bs[nq+q+0][r] = bf2f(w.x); Bs[nq+q+1][r] = bf2f(w.y);
    Bs[nq+q+2][r] = bf2f(w.z); Bs[nq+q+3][r] = bf2f(w.w);
  }
  __syncthreads();
  const int tx = tid & 15, ty = tid >> 4;
  float acc[4][4];
  #pragma unroll
  for (int i = 0; i < 4; ++i)
    #pragma unroll
    for (int j = 0; j < 4; ++j) acc[i][j] = 0.f;
  #pragma unroll 8
  for (int n = 0; n < 64; ++n) {
    float4 a = *(const float4*)&Cs[n][ty << 2];
    float4 bb = *(const float4*)&Bs[n][tx << 2];
    float av[4] = {a.x, a.y, a.z, a.w};
    float bv[4] = {bb.x, bb.y, bb.z, bb.w};
    #pragma unroll
    for (int i = 0; i < 4; ++i)
      #pragma unroll
      for (int j = 0; j < 4; ++j) acc[i][j] += av[i] * bv[j];
  }
  float* spp = scores + (size_t)(b * NC + c) * CHUNK * CHUNK;
  #pragma unroll
  for (int i = 0; i < 4; ++i)
    #pragma unroll
    for (int j = 0; j < 4; ++j)
      spp[(size_t)(s0 + (ty << 2) + i) * CHUNK + z0 + (tx << 2) + j] = acc[i][j];
}

// ---------------- Y = (scores*L)@xdt + exp(cum)*C@prev^T + D*x ----------------
// Output y goes into zx dead columns [D_INNER, 2*D_INNER), row stride D_IN_PROJ.
__global__ __launch_bounds__(256) void ydiag_off_k(const u16* __restrict__ xBC,
                                                   const float* __restrict__ dtf,
                                                   const float* __restrict__ cumf,
                                                   const float* __restrict__ scores,
                                                   const float* __restrict__ prevst,
                                                   const float* __restrict__ df,
                                                   u16* __restrict__ y) {
  const int hx = blockIdx.x;           // 0..63
  const int h = hx >> 1, shalf = hx & 1;
  const int c = blockIdx.y, b = blockIdx.z;
  const int tid = threadIdx.x;
  const int s_base = shalf << 7;
  __shared__ __align__(16) float cum_sh[CHUNK];
  __shared__ __align__(16) float sA[128 * 33];   // sL / C*exp(cum): row stride 33
  __shared__ __align__(16) float sB[32 * 132];   // xdt / prev^T  : row stride 132
  const int rowbase = b * SEQLEN + c * CHUNK;
  const size_t cumbase = ((size_t)(b * NC + c) * NHEADS + h) * CHUNK;
  cum_sh[tid] = cumf[cumbase + tid];
  const int tx = tid & 15, ty = tid >> 4;
  const int p0 = tx << 3, sl0 = ty << 3;
  const float* scb = scores + ((size_t)(b * NC + c) * CHUNK + s_base) * CHUNK;
  float acc[8][8];
  #pragma unroll
  for (int i = 0; i < 8; ++i)
    #pragma unroll
    for (int j = 0; j < 8; ++j) acc[i][j] = 0.f;
  __syncthreads();
  // ---- Y_diag over z-slabs of 32 ----
  for (int z0 = 0; z0 < CHUNK; z0 += 32) {
    {
      int zz = tid >> 3, pq = (tid & 7) << 4;
      int row = rowbase + z0 + zz;
      float dtv = dtf[(size_t)row * NHEADS + h];
      const u16* xp = xBC + (size_t)row * CONV_DIM + h * D_HEAD + pq;
      float* dst = &sB[zz * 132 + pq];
      #pragma unroll
      for (int q = 0; q < 4; ++q) {
        ushort4 v = *(const ushort4*)(xp + q * 4);
        dst[q*4+0] = bf2f(v.x) * dtv; dst[q*4+1] = bf2f(v.y) * dtv;
        dst[q*4+2] = bf2f(v.z) * dtv; dst[q*4+3] = bf2f(v.w) * dtv;
      }
    }
    {
      int ss = tid >> 1, zq = (tid & 1) << 4;
      int sg = s_base + ss;
      float cs = cum_sh[sg];
      const float* srow = scb + (size_t)ss * CHUNK + z0 + zq;
      float* dst = &sA[ss * 33 + zq];
      #pragma unroll
      for (int q = 0; q < 16; ++q) {
        int z = z0 + zq + q;
        float ex = __expf(fminf(cs - cum_sh[z], 0.f));   // clamp: no transient inf
        dst[q] = (z <= sg) ? srow[q] * ex : 0.f;
      }
    }
    __syncthreads();
    #pragma unroll 4
    for (int z = 0; z < 32; ++z) {
      float4 xa = *(const float4*)&sB[z * 132 + p0];
      float4 xb = *(const float4*)&sB[z * 132 + p0 + 4];
      float sv[8];
      #pragma unroll
      for (int i = 0; i < 8; ++i) sv[i] = sA[(sl0 + i) * 33 + z];
      #pragma unroll
      for (int i = 0; i < 8; ++i) {
        acc[i][0] += sv[i] * xa.x; acc[i][1] += sv[i] * xa.y;
        acc[i][2] += sv[i] * xa.z; acc[i][3] += sv[i] * xa.w;
        acc[i][4] += sv[i] * xb.x; acc[i][5] += sv[i] * xb.y;
        acc[i][6] += sv[i] * xb.z; acc[i][7] += sv[i] * xb.w;
      }
    }
    __syncthreads();
  }
  // ---- Y_off over n-slabs of 32 ----
  for (int n0s = 0; n0s < D_STATE; n0s += 32) {
    {
      int pp = tid >> 1, nq = (tid & 1) << 4;
      const float* pv = prevst + ((size_t)(b * NC + c) * NHEADS + h) * (D_HEAD * D_STATE)
                        + (size_t)pp * D_STATE + n0s + nq;
      #pragma unroll
      for (int q = 0; q < 16; ++q) sB[(nq + q) * 132 + pp] = pv[q];
      int ss = tid >> 1;
      float es = __expf(fminf(cum_sh[s_base + ss], 0.f));
      const u16* cp = xBC + (size_t)(rowbase + s_base + ss) * CONV_DIM + D_INNER + D_STATE + n0s + nq;
      float* dst = &sA[ss * 33 + nq];
      #pragma unroll
      for (int q = 0; q < 4; ++q) {
        ushort4 v = *(const ushort4*)(cp + q * 4);
        dst[q*4+0] = bf2f(v.x) * es; dst[q*4+1] = bf2f(v.y) * es;
        dst[q*4+2] = bf2f(v.z) * es; dst[q*4+3] = bf2f(v.w) * es;
      }
    }
    __syncthreads();
    #pragma unroll 4
    for (int n = 0; n < 32; ++n) {
      float4 pa = *(const float4*)&sB[n * 132 + p0];
      float4 pb = *(const float4*)&sB[n * 132 + p0 + 4];
      float cv[8];
      #pragma unroll
      for (int i = 0; i < 8; ++i) cv[i] = sA[(sl0 + i) * 33 + n];
      #pragma unroll
      for (int i = 0; i < 8; ++i) {
        acc[i][0] += cv[i] * pa.x; acc[i][1] += cv[i] * pa.y;
        acc[i][2] += cv[i] * pa.z; acc[i][3] += cv[i] * pa.w;
        acc[i][4] += cv[i] * pb.x; acc[i][5] += cv[i] * pb.y;
        acc[i][6] += cv[i] * pb.z; acc[i][7] += cv[i] * pb.w;
      }
    }
    __syncthreads();
  }
  float Dv = df[h];
  #pragma unroll
  for (int i = 0; i < 8; ++i) {
    int row = rowbase + s_base + sl0 + i;
    const u16* xp = xBC + (size_t)row * CONV_DIM + h * D_HEAD + p0;
    u16* yp = y + (size_t)row * D_IN_PROJ + D_INNER + h * D_HEAD + p0;
    #pragma unroll
    for (int j = 0; j < 8; ++j) yp[j] = f2bf(acc[i][j] + bf2f(xp[j]) * Dv);
  }
}

// ---------------- gating + RMSNorm (in-place within zx buffer) ----------------
__global__ __launch_bounds__(256) void gatenorm_k(u16* __restrict__ zx,
                                                  const float* __restrict__ nwf) {
  const int row = blockIdx.x;
  const int tid = threadIdx.x;
  u16* zrow = zx + (size_t)row * D_IN_PROJ;
  u16* yrow = zrow + D_INNER;
  float vals[16];
  float ss = 0.f;
  #pragma unroll
  for (int q = 0; q < 16; ++q) {
    int e = tid + q * 256;
    float yv = bf2f(yrow[e]);
    float zv = bf2f(zrow[e]);
    float g = yv * (zv / (1.f + __expf(-zv)));
    vals[q] = g;
    ss += g * g;
  }
  #pragma unroll
  for (int off = 1; off < 64; off <<= 1) ss += __shfl_xor(ss, off);
  __shared__ float red[4];
  int lane = tid & 63, wv = tid >> 6;
  if (lane == 0) red[wv] = ss;
  __syncthreads();
  float tot = red[0] + red[1] + red[2] + red[3];
  float scale = rsqrtf(tot * (1.f / D_INNER) + EPS_F);
  #pragma unroll
  for (int q = 0; q < 16; ++q) {
    int e = tid + q * 256;
    yrow[e] = f2bf(vals[q] * scale * nwf[e]);
  }
}

extern "C" void kernel_launch(void* const* d_in, const int* in_sizes, int n_in,
                              void* d_out, int out_size, void* d_ws, size_t ws_size,
                              hipStream_t stream) {
  (void)in_sizes; (void)n_in; (void)out_size; (void)ws_size;
  const void* u       = d_in[0];
  const void* W_in    = d_in[1];
  const void* conv_w  = d_in[2];
  const void* conv_b  = d_in[3];
  const void* dt_bias = d_in[4];
  const void* A_log   = d_in[5];
  const void* Dv      = d_in[6];
  const void* norm_w  = d_in[7];
  const void* W_out   = d_in[8];

  char* w = (char*)d_ws;
  size_t o = 0;
  int*   flag  = (int*)(w + o);    o += 256;
  float* smallp= (float*)(w + o);  o += ((size_t)N_SMALL * 4 + 255) & ~(size_t)255;   // ~101 KB
  u16* zx      = (u16*)(w + o);    o += (size_t)ROWS * D_IN_PROJ * 2;                 // 136.8 MB
  u16* xbc     = (u16*)(w + o);    o += (size_t)ROWS * CONV_DIM * 2;                  //  69.2 MB
  float* dtf   = (float*)(w + o);  o += (size_t)ROWS * NHEADS * 4;                    //   1.0 MB
  float* cumf  = (float*)(w + o);  o += (size_t)BATCH * NC * NHEADS * CHUNK * 4;      //   1.0 MB
  float* cdec  = (float*)(w + o);  o += ((size_t)BATCH * NC * NHEADS * 4 + 255) & ~(size_t)255;
  float* states= (float*)(w + o);  o += (size_t)BATCH * NC * NHEADS * D_HEAD * D_STATE * 4; // 33.5 MB
  float* scores= (float*)(w + o);  o += (size_t)BATCH * NC * CHUNK * CHUNK * 4;       //   8.4 MB
  // total ~250 MB

  float* cwf  = smallp;
  float* cbf  = smallp + N_CW;
  float* dtbf = cbf + N_CB;
  float* alogf= dtbf + 32;
  float* df   = alogf + 32;
  float* nwf  = df + 32;

  // 0. dtype detect + small-param convert
  detect_k<<<1, 256, 0, stream>>>((const u16*)W_in, flag);
  convert_small_k<<<(N_SMALL + 255) / 256, 256, 0, stream>>>(
      conv_w, conv_b, dt_bias, A_log, Dv, norm_w, flag, smallp);

  // 1. in_proj (dual dtype)
  dim3 g1((D_IN_PROJ + 127) / 128, ROWS / 128);
  gemm_nt<0,0,0><<<g1, 256, 0, stream>>>(u, D_MODEL, W_in, zx, ROWS, D_IN_PROJ, D_MODEL, flag, 0);
  gemm_nt<1,1,0><<<g1, 256, 0, stream>>>(u, D_MODEL, W_in, zx, ROWS, D_IN_PROJ, D_MODEL, flag, 1);
  // 2. conv + silu
  conv_silu_k<<<dim3((CONV_DIM + 255) / 256, ROWS), 256, 0, stream>>>(zx, cwf, cbf, xbc);
  // 3. dt softplus
  dt_softplus_k<<<dim3(ROWS * NHEADS / 256), 256, 0, stream>>>(zx, dtbf, dtf);
  // 4. chunk states
  chunk_states_k<<<dim3(NHEADS, NC, BATCH), 256, 0, stream>>>(xbc, dtf, alogf, cumf, cdec, states);
  // 5. scan (in-place)
  scan_k<<<dim3(NHEADS, BATCH), 256, 0, stream>>>(states, cdec);
  // 6. scores
  scores_k<<<dim3(16, NC, BATCH), 256, 0, stream>>>(xbc, scores);
  // 7. Y (into zx dead cols [4096,8192))
  ydiag_off_k<<<dim3(NHEADS * 2, NC, BATCH), 256, 0, stream>>>(
      xbc, dtf, cumf, scores, states, df, zx);
  // 8. gate + norm (in-place)
  gatenorm_k<<<dim3(ROWS), 256, 0, stream>>>(zx, nwf);
  // 9. out_proj (dual store dtype)
  dim3 g9(D_MODEL / 128, ROWS / 128);
  gemm_nt<0,0,0><<<g9, 256, 0, stream>>>(zx + D_INNER, D_IN_PROJ, W_out, d_out, ROWS, D_MODEL, D_INNER, flag, 0);
  gemm_nt<0,1,1><<<g9, 256, 0, stream>>>(zx + D_INNER, D_IN_PROJ, W_out, d_out, ROWS, D_MODEL, D_INNER, flag, 1);
}

// Round 4
// 1389.410 us; speedup vs baseline: 4.2410x; 4.2410x over previous
//
#include <hip/hip_runtime.h>
#include <cstddef>

// Mamba2 forward, MI355X. bf16 MFMA GEMMs (m97 structure), fp32/bf16 input autodetect.
//  0 detect_k / convert_small_k / to_bf16_k(u, W_in)
//  1 gemm_mfma      : zxbcdt = u_b @ Win_b^T    (bf16 MFMA, fp32 acc, bf16 out)
//  2 conv_silu_k    : causal conv4 + SiLU
//  3 dt_softplus_k  : dt = softplus(raw + dt_bias)
//  4 chunk_states_k : per-chunk cum(dA), decay, states = B^T(decay*dt*x)
//  5 scan_k         : in-place inter-chunk state scan
//  6 scores_k       : scores = C.B^T per (b,chunk)   (head-independent, g=1)
//  7 ydiag_off_k    : Y = (scores*L)@xdt + exp(cum)*C@prev^T + D*x  -> zx dead cols
//  7.5 to_bf16_k(W_out) into xbc region (xbc dead after step 7)
//  8 gatenorm_k     : yg = y*silu(z); RMSNorm (in-place)
//  9 gemm_mfma      : out = yn @ Wout_b^T  (store fp32/bf16 per flag)
//
// Workspace (~250 MB, proven safe):
//   zx 136.8 | R2 69.2 (Win_b -> xbc -> Wout_b) | R3 33.55 (u_b -> states)
//   scores 8.4 | dtf 1.0 | cumf 1.0 | cdec/small ~0.1

#define D_MODEL 2048
#define D_STATE 64
#define D_HEAD 128
#define CHUNK 256
#define D_INNER 4096
#define NHEADS 32
#define CONV_DIM 4224
#define D_IN_PROJ 8352
#define NPAD 8448
#define BATCH 2
#define SEQLEN 4096
#define NC 16
#define ROWS 8192
#define EPS_F 1e-5f

typedef unsigned short u16;
typedef __attribute__((ext_vector_type(8))) short bf16x8;
typedef __attribute__((ext_vector_type(4))) float f32x4;

__device__ __forceinline__ float bf2f(u16 u) { return __uint_as_float(((unsigned)u) << 16); }
__device__ __forceinline__ u16 f2bf(float f) {
  unsigned x = __float_as_uint(f);
  x += 0x7FFFu + ((x >> 16) & 1u);
  return (u16)(x >> 16);
}

// ---------------- dtype detection ----------------
__global__ void detect_k(const u16* __restrict__ win, int* __restrict__ flag) {
  __shared__ int cnt;
  if (threadIdx.x == 0) cnt = 0;
  __syncthreads();
  int c = 0;
  for (int i = threadIdx.x; i < 8192; i += 256) {
    u16 x = win[i];
    int e = (x >> 7) & 0xFF;
    if (e != 0 && (e < 90 || e > 160)) c++;
  }
  atomicAdd(&cnt, c);
  __syncthreads();
  if (threadIdx.x == 0) *flag = (cnt > 512) ? 1 : 0;
}

// ---------------- convert small params to fp32 ws arrays ----------------
__device__ __forceinline__ float readin(const void* p, int i, int isf32) {
  return isf32 ? ((const float*)p)[i] : bf2f(((const u16*)p)[i]);
}
#define N_CW 16896
#define N_CB 4224
#define N_SMALL (N_CW + N_CB + 32 + 32 + 32 + 4096)
__global__ __launch_bounds__(256) void convert_small_k(const void* cw, const void* cb,
                                                       const void* dtb, const void* alog,
                                                       const void* Dv, const void* nw,
                                                       const int* __restrict__ flag,
                                                       float* __restrict__ dst) {
  int idx = blockIdx.x * 256 + threadIdx.x;
  if (idx >= N_SMALL) return;
  int f = *flag;
  float v; int o = idx;
  if (o < N_CW) { v = readin(cw, o, f); }
  else if ((o -= N_CW) < N_CB) { v = readin(cb, o, f); }
  else if ((o -= N_CB) < 32) { v = readin(dtb, o, f); }
  else if ((o -= 32) < 32) { v = readin(alog, o, f); }
  else if ((o -= 32) < 32) { v = readin(Dv, o, f); }
  else { o -= 32; v = readin(nw, o, f); }
  dst[idx] = v;
}

// ---------------- convert big tensor -> packed bf16 (zero-pad tail) ----------------
__global__ __launch_bounds__(256) void to_bf16_k(const void* __restrict__ src,
                                                 u16* __restrict__ dst,
                                                 long n_src, long n_total,
                                                 const int* __restrict__ flag) {
  long i = ((long)blockIdx.x * 256 + threadIdx.x) * 8;
  if (i >= n_total) return;
  ushort4 o0, o1;
  if (i >= n_src) {
    o0.x = o0.y = o0.z = o0.w = 0; o1 = o0;
  } else if (*flag) {
    float4 a = *((const float4*)src + (i >> 2));
    float4 b = *((const float4*)src + (i >> 2) + 1);
    o0.x = f2bf(a.x); o0.y = f2bf(a.y); o0.z = f2bf(a.z); o0.w = f2bf(a.w);
    o1.x = f2bf(b.x); o1.y = f2bf(b.y); o1.z = f2bf(b.z); o1.w = f2bf(b.w);
  } else {
    o0 = *((const ushort4*)src + (i >> 2));
    o1 = *((const ushort4*)src + (i >> 2) + 1);
  }
  *(ushort4*)(dst + i) = o0;
  *(ushort4*)(dst + i + 4) = o1;
}

// ---------------- MFMA GEMM: C[M,N](ldc) = A[M,K](lda) @ B[N,K]^T ----------------
// B is packed (lda == K), rows padded to a multiple of 128 (zero-filled).
// 256 thr = 4 waves; 128x128 block tile; wave = 64x64 (4x4 of 16x16x32 MFMA).
// OUTDYN: 1 -> store fp32 if *flagp else bf16 (out_proj); 0 -> bf16 store.
template <int OUTDYN>
__global__ __launch_bounds__(256) void gemm_mfma(const u16* __restrict__ A, int lda,
                                                 const u16* __restrict__ B,
                                                 void* __restrict__ Cv, int ldc,
                                                 int M, int N, int K,
                                                 const int* __restrict__ flagp) {
  __shared__ __align__(16) u16 As[128 * 32];
  __shared__ __align__(16) u16 Bs[128 * 32];
  const int tid = threadIdx.x;
  const int bm = blockIdx.y << 7, bn = blockIdx.x << 7;
  const int lane = tid & 63, w = tid >> 6;
  const int wr = (w >> 1) << 6, wc = (w & 1) << 6;   // wave 64x64 quadrant
  // staging: thread t -> row t>>2 (round 0) / 64+(t>>2) (round 1), k-seg (t&3)*8
  const int srow = tid >> 2, sk = (tid & 3) << 3;
  const u16* ag = A + (size_t)(bm + srow) * lda + sk;
  const u16* bg = B + (size_t)(bn + srow) * K + sk;
  u16* lA0 = &As[tid << 3];
  u16* lA1 = &As[2048 + (tid << 3)];
  u16* lB0 = &Bs[tid << 3];
  u16* lB1 = &Bs[2048 + (tid << 3)];
  const size_t astride = (size_t)64 * lda, bstride = (size_t)64 * K;

  f32x4 acc[4][4];
  #pragma unroll
  for (int i = 0; i < 4; ++i)
    #pragma unroll
    for (int j = 0; j < 4; ++j) { acc[i][j].x = 0.f; acc[i][j].y = 0.f; acc[i][j].z = 0.f; acc[i][j].w = 0.f; }

  const int m16 = lane & 15;          // row/col within 16-tile
  const int kq = (lane >> 4) << 3;    // k offset of this lane's quad

  for (int k0 = 0; k0 < K; k0 += 32) {
    __syncthreads();   // prior iter's ds_reads done before overwrite
    __builtin_amdgcn_global_load_lds((const __attribute__((address_space(1))) void*)(ag + k0),
                                     (__attribute__((address_space(3))) void*)lA0, 16, 0, 0);
    __builtin_amdgcn_global_load_lds((const __attribute__((address_space(1))) void*)(ag + k0 + astride),
                                     (__attribute__((address_space(3))) void*)lA1, 16, 0, 0);
    __builtin_amdgcn_global_load_lds((const __attribute__((address_space(1))) void*)(bg + k0),
                                     (__attribute__((address_space(3))) void*)lB0, 16, 0, 0);
    __builtin_amdgcn_global_load_lds((const __attribute__((address_space(1))) void*)(bg + k0 + bstride),
                                     (__attribute__((address_space(3))) void*)lB1, 16, 0, 0);
    __syncthreads();   // vmcnt drained by barrier semantics
    bf16x8 af[4], bfr[4];
    #pragma unroll
    for (int i = 0; i < 4; ++i)
      af[i] = *(const bf16x8*)&As[(wr + i * 16 + m16) * 32 + kq];
    #pragma unroll
    for (int j = 0; j < 4; ++j)
      bfr[j] = *(const bf16x8*)&Bs[(wc + j * 16 + m16) * 32 + kq];
    #pragma unroll
    for (int i = 0; i < 4; ++i)
      #pragma unroll
      for (int j = 0; j < 4; ++j)
        acc[i][j] = __builtin_amdgcn_mfma_f32_16x16x32_bf16(af[i], bfr[j], acc[i][j], 0, 0, 0);
  }

  // epilogue: C/D layout col = lane&15, row = (lane>>4)*4 + reg
  const int r4 = (lane >> 4) << 2;
  int f = 0;
  if (OUTDYN) f = *flagp;
  #pragma unroll
  for (int i = 0; i < 4; ++i) {
    #pragma unroll
    for (int r = 0; r < 4; ++r) {
      size_t rowoff = (size_t)(bm + wr + i * 16 + r4 + r) * ldc;
      #pragma unroll
      for (int j = 0; j < 4; ++j) {
        int col = bn + wc + j * 16 + m16;
        if (col < N) {
          float v = acc[i][j][r];
          if (OUTDYN && f) ((float*)Cv)[rowoff + col] = v;
          else             ((u16*)Cv)[rowoff + col] = f2bf(v);
        }
      }
    }
  }
}

// ---------------- causal conv4 + SiLU ----------------
__global__ __launch_bounds__(256) void conv_silu_k(const u16* __restrict__ zx,
                                                   const float* __restrict__ cwf,
                                                   const float* __restrict__ cbf,
                                                   u16* __restrict__ xBC) {
  int c = blockIdx.x * 256 + threadIdx.x;
  if (c >= CONV_DIM) return;
  int row = blockIdx.y;
  int b = row >> 12, l = row & 4095;
  float acc = cbf[c];
  #pragma unroll
  for (int k = 0; k < 4; ++k) {
    int li = l - 3 + k;
    if (li >= 0)
      acc += bf2f(zx[(size_t)(b * SEQLEN + li) * D_IN_PROJ + D_INNER + c]) * cwf[c * 4 + k];
  }
  acc = acc / (1.f + __expf(-acc));
  xBC[(size_t)row * CONV_DIM + c] = f2bf(acc);
}

// ---------------- dt = softplus(raw + bias) ----------------
__global__ __launch_bounds__(256) void dt_softplus_k(const u16* __restrict__ zx,
                                                     const float* __restrict__ dtbf,
                                                     float* __restrict__ dtf) {
  int idx = blockIdx.x * 256 + threadIdx.x;   // ROWS*NHEADS
  int i = idx >> 5, h = idx & 31;
  float x = bf2f(zx[(size_t)i * D_IN_PROJ + (D_INNER + CONV_DIM) + h]) + dtbf[h];
  float sp = (x > 20.f) ? x : log1pf(__expf(fminf(x, 20.f)));
  dtf[idx] = sp;
}

// ---------------- per-chunk cum, decay, states ----------------
__global__ __launch_bounds__(256) void chunk_states_k(const u16* __restrict__ xBC,
                                                      const float* __restrict__ dtf,
                                                      const float* __restrict__ alogf,
                                                      float* __restrict__ cumf,
                                                      float* __restrict__ cdec,
                                                      float* __restrict__ states) {
  const int h = blockIdx.x, c = blockIdx.y, b = blockIdx.z;
  const int tid = threadIdx.x;
  __shared__ __align__(16) float dt_sh[CHUNK];
  __shared__ __align__(16) float cum_sh[CHUNK];
  __shared__ __align__(16) float w_sh[CHUNK];
  __shared__ __align__(16) float xs[64][132];
  __shared__ __align__(16) float Bst[64][68];
  const int rowbase = b * SEQLEN + c * CHUNK;
  dt_sh[tid] = dtf[(size_t)(rowbase + tid) * NHEADS + h];
  __syncthreads();
  if (tid == 0) {
    float Aneg = -__expf(alogf[h]);
    float s = 0.f;
    for (int z = 0; z < CHUNK; ++z) { s += dt_sh[z] * Aneg; cum_sh[z] = s; }
  }
  __syncthreads();
  float cl = cum_sh[CHUNK - 1];
  w_sh[tid] = __expf(fminf(cl - cum_sh[tid], 0.f)) * dt_sh[tid];
  cumf[((size_t)(b * NC + c) * NHEADS + h) * CHUNK + tid] = cum_sh[tid];
  if (tid == 0) cdec[(b * NC + c) * NHEADS + h] = __expf(fminf(cl, 0.f));
  __syncthreads();
  const int tx = tid & 15, ty = tid >> 4;
  const int p0 = tx << 3, n0 = ty << 2;
  float acc[8][4];
  #pragma unroll
  for (int i = 0; i < 8; ++i)
    #pragma unroll
    for (int j = 0; j < 4; ++j) acc[i][j] = 0.f;
  for (int z0 = 0; z0 < CHUNK; z0 += 64) {
    int zz = tid >> 2;
    int pq = (tid & 3) << 5;
    const u16* xp = xBC + (size_t)(rowbase + z0 + zz) * CONV_DIM + h * D_HEAD + pq;
    #pragma unroll
    for (int q = 0; q < 8; ++q) {
      ushort4 v = *(const ushort4*)(xp + q * 4);
      xs[zz][pq + q*4 + 0] = bf2f(v.x); xs[zz][pq + q*4 + 1] = bf2f(v.y);
      xs[zz][pq + q*4 + 2] = bf2f(v.z); xs[zz][pq + q*4 + 3] = bf2f(v.w);
    }
    int nq = (tid & 3) << 4;
    const u16* bpp = xBC + (size_t)(rowbase + z0 + zz) * CONV_DIM + D_INNER + nq;
    float wz = w_sh[z0 + zz];
    #pragma unroll
    for (int q = 0; q < 4; ++q) {
      ushort4 v = *(const ushort4*)(bpp + q * 4);
      Bst[zz][nq + q*4 + 0] = bf2f(v.x) * wz; Bst[zz][nq + q*4 + 1] = bf2f(v.y) * wz;
      Bst[zz][nq + q*4 + 2] = bf2f(v.z) * wz; Bst[zz][nq + q*4 + 3] = bf2f(v.w) * wz;
    }
    __syncthreads();
    #pragma unroll 4
    for (int z = 0; z < 64; ++z) {
      float4 x0 = *(const float4*)&xs[z][p0];
      float4 x1 = *(const float4*)&xs[z][p0 + 4];
      float4 bv = *(const float4*)&Bst[z][n0];
      float xv[8] = {x0.x, x0.y, x0.z, x0.w, x1.x, x1.y, x1.z, x1.w};
      float bb[4] = {bv.x, bv.y, bv.z, bv.w};
      #pragma unroll
      for (int i = 0; i < 8; ++i)
        #pragma unroll
        for (int j = 0; j < 4; ++j) acc[i][j] += xv[i] * bb[j];
    }
    __syncthreads();
  }
  float* sp = states + ((size_t)(b * NC + c) * NHEADS + h) * (D_HEAD * D_STATE);
  #pragma unroll
  for (int i = 0; i < 8; ++i)
    #pragma unroll
    for (int j = 0; j < 4; ++j)
      sp[(size_t)(p0 + i) * D_STATE + n0 + j] = acc[i][j];
}

// ---------------- inter-chunk scan (IN-PLACE: states -> prev_states) ----------------
__global__ __launch_bounds__(256) void scan_k(float* __restrict__ states,
                                              const float* __restrict__ cdec) {
  const int h = blockIdx.x, b = blockIdx.y;
  const int tid = threadIdx.x;
  float carry[32];
  #pragma unroll
  for (int j = 0; j < 32; ++j) carry[j] = 0.f;
  for (int c = 0; c < NC; ++c) {
    size_t base = ((size_t)(b * NC + c) * NHEADS + h) * (D_HEAD * D_STATE);
    float dec = cdec[(b * NC + c) * NHEADS + h];
    #pragma unroll
    for (int j = 0; j < 32; ++j) {
      size_t e = base + tid + j * 256;
      float s = states[e];
      states[e] = carry[j];
      carry[j] = carry[j] * dec + s;
    }
  }
}

// ---------------- scores = C . B^T  (head-independent) ----------------
__global__ __launch_bounds__(256) void scores_k(const u16* __restrict__ xBC,
                                                float* __restrict__ scores) {
  const int bx = blockIdx.x;            // 0..15
  const int c = blockIdx.y, b = blockIdx.z;
  const int s0 = (bx >> 2) << 6, z0 = (bx & 3) << 6;
  __shared__ __align__(16) float Cs[64][68];   // [n][s]
  __shared__ __align__(16) float Bs2[64][68];  // [n][z]
  const int tid = threadIdx.x;
  const int rowbase = b * SEQLEN + c * CHUNK;
  int r = tid >> 2, nq = (tid & 3) << 4;
  const u16* cp = xBC + (size_t)(rowbase + s0 + r) * CONV_DIM + D_INNER + D_STATE + nq;
  const u16* bp = xBC + (size_t)(rowbase + z0 + r) * CONV_DIM + D_INNER + nq;
  #pragma unroll
  for (int q = 0; q < 16; q += 4) {
    ushort4 v = *(const ushort4*)(cp + q);
    Cs[nq+q+0][r] = bf2f(v.x); Cs[nq+q+1][r] = bf2f(v.y);
    Cs[nq+q+2][r] = bf2f(v.z); Cs[nq+q+3][r] = bf2f(v.w);
    ushort4 w2 = *(const ushort4*)(bp + q);
    Bs2[nq+q+0][r] = bf2f(w2.x); Bs2[nq+q+1][r] = bf2f(w2.y);
    Bs2[nq+q+2][r] = bf2f(w2.z); Bs2[nq+q+3][r] = bf2f(w2.w);
  }
  __syncthreads();
  const int tx = tid & 15, ty = tid >> 4;
  float acc[4][4];
  #pragma unroll
  for (int i = 0; i < 4; ++i)
    #pragma unroll
    for (int j = 0; j < 4; ++j) acc[i][j] = 0.f;
  #pragma unroll 8
  for (int n = 0; n < 64; ++n) {
    float4 a = *(const float4*)&Cs[n][ty << 2];
    float4 bb = *(const float4*)&Bs2[n][tx << 2];
    float av[4] = {a.x, a.y, a.z, a.w};
    float bv[4] = {bb.x, bb.y, bb.z, bb.w};
    #pragma unroll
    for (int i = 0; i < 4; ++i)
      #pragma unroll
      for (int j = 0; j < 4; ++j) acc[i][j] += av[i] * bv[j];
  }
  float* spp = scores + (size_t)(b * NC + c) * CHUNK * CHUNK;
  #pragma unroll
  for (int i = 0; i < 4; ++i)
    #pragma unroll
    for (int j = 0; j < 4; ++j)
      spp[(size_t)(s0 + (ty << 2) + i) * CHUNK + z0 + (tx << 2) + j] = acc[i][j];
}

// ---------------- Y = (scores*L)@xdt + exp(cum)*C@prev^T + D*x ----------------
__global__ __launch_bounds__(256) void ydiag_off_k(const u16* __restrict__ xBC,
                                                   const float* __restrict__ dtf,
                                                   const float* __restrict__ cumf,
                                                   const float* __restrict__ scores,
                                                   const float* __restrict__ prevst,
                                                   const float* __restrict__ df,
                                                   u16* __restrict__ y) {
  const int hx = blockIdx.x;           // 0..63
  const int h = hx >> 1, shalf = hx & 1;
  const int c = blockIdx.y, b = blockIdx.z;
  const int tid = threadIdx.x;
  const int s_base = shalf << 7;
  __shared__ __align__(16) float cum_sh[CHUNK];
  __shared__ __align__(16) float sA[128 * 33];
  __shared__ __align__(16) float sB[32 * 132];
  const int rowbase = b * SEQLEN + c * CHUNK;
  const size_t cumbase = ((size_t)(b * NC + c) * NHEADS + h) * CHUNK;
  cum_sh[tid] = cumf[cumbase + tid];
  const int tx = tid & 15, ty = tid >> 4;
  const int p0 = tx << 3, sl0 = ty << 3;
  const float* scb = scores + ((size_t)(b * NC + c) * CHUNK + s_base) * CHUNK;
  float acc[8][8];
  #pragma unroll
  for (int i = 0; i < 8; ++i)
    #pragma unroll
    for (int j = 0; j < 8; ++j) acc[i][j] = 0.f;
  __syncthreads();
  for (int z0 = 0; z0 < CHUNK; z0 += 32) {
    {
      int zz = tid >> 3, pq = (tid & 7) << 4;
      int row = rowbase + z0 + zz;
      float dtv = dtf[(size_t)row * NHEADS + h];
      const u16* xp = xBC + (size_t)row * CONV_DIM + h * D_HEAD + pq;
      float* dst = &sB[zz * 132 + pq];
      #pragma unroll
      for (int q = 0; q < 4; ++q) {
        ushort4 v = *(const ushort4*)(xp + q * 4);
        dst[q*4+0] = bf2f(v.x) * dtv; dst[q*4+1] = bf2f(v.y) * dtv;
        dst[q*4+2] = bf2f(v.z) * dtv; dst[q*4+3] = bf2f(v.w) * dtv;
      }
    }
    {
      int ss = tid >> 1, zq = (tid & 1) << 4;
      int sg = s_base + ss;
      float cs = cum_sh[sg];
      const float* srow = scb + (size_t)ss * CHUNK + z0 + zq;
      float* dst = &sA[ss * 33 + zq];
      #pragma unroll
      for (int q = 0; q < 16; ++q) {
        int z = z0 + zq + q;
        float ex = __expf(fminf(cs - cum_sh[z], 0.f));
        dst[q] = (z <= sg) ? srow[q] * ex : 0.f;
      }
    }
    __syncthreads();
    #pragma unroll 4
    for (int z = 0; z < 32; ++z) {
      float4 xa = *(const float4*)&sB[z * 132 + p0];
      float4 xb = *(const float4*)&sB[z * 132 + p0 + 4];
      float sv[8];
      #pragma unroll
      for (int i = 0; i < 8; ++i) sv[i] = sA[(sl0 + i) * 33 + z];
      #pragma unroll
      for (int i = 0; i < 8; ++i) {
        acc[i][0] += sv[i] * xa.x; acc[i][1] += sv[i] * xa.y;
        acc[i][2] += sv[i] * xa.z; acc[i][3] += sv[i] * xa.w;
        acc[i][4] += sv[i] * xb.x; acc[i][5] += sv[i] * xb.y;
        acc[i][6] += sv[i] * xb.z; acc[i][7] += sv[i] * xb.w;
      }
    }
    __syncthreads();
  }
  for (int n0s = 0; n0s < D_STATE; n0s += 32) {
    {
      int pp = tid >> 1, nq = (tid & 1) << 4;
      const float* pv = prevst + ((size_t)(b * NC + c) * NHEADS + h) * (D_HEAD * D_STATE)
                        + (size_t)pp * D_STATE + n0s + nq;
      #pragma unroll
      for (int q = 0; q < 16; ++q) sB[(nq + q) * 132 + pp] = pv[q];
      int ss = tid >> 1;
      float es = __expf(fminf(cum_sh[s_base + ss], 0.f));
      const u16* cp = xBC + (size_t)(rowbase + s_base + ss) * CONV_DIM + D_INNER + D_STATE + n0s + nq;
      float* dst = &sA[ss * 33 + nq];
      #pragma unroll
      for (int q = 0; q < 4; ++q) {
        ushort4 v = *(const ushort4*)(cp + q * 4);
        dst[q*4+0] = bf2f(v.x) * es; dst[q*4+1] = bf2f(v.y) * es;
        dst[q*4+2] = bf2f(v.z) * es; dst[q*4+3] = bf2f(v.w) * es;
      }
    }
    __syncthreads();
    #pragma unroll 4
    for (int n = 0; n < 32; ++n) {
      float4 pa = *(const float4*)&sB[n * 132 + p0];
      float4 pb = *(const float4*)&sB[n * 132 + p0 + 4];
      float cv[8];
      #pragma unroll
      for (int i = 0; i < 8; ++i) cv[i] = sA[(sl0 + i) * 33 + n];
      #pragma unroll
      for (int i = 0; i < 8; ++i) {
        acc[i][0] += cv[i] * pa.x; acc[i][1] += cv[i] * pa.y;
        acc[i][2] += cv[i] * pa.z; acc[i][3] += cv[i] * pa.w;
        acc[i][4] += cv[i] * pb.x; acc[i][5] += cv[i] * pb.y;
        acc[i][6] += cv[i] * pb.z; acc[i][7] += cv[i] * pb.w;
      }
    }
    __syncthreads();
  }
  float Dvv = df[h];
  #pragma unroll
  for (int i = 0; i < 8; ++i) {
    int row = rowbase + s_base + sl0 + i;
    const u16* xp = xBC + (size_t)row * CONV_DIM + h * D_HEAD + p0;
    u16* yp = y + (size_t)row * D_IN_PROJ + D_INNER + h * D_HEAD + p0;
    #pragma unroll
    for (int j = 0; j < 8; ++j) yp[j] = f2bf(acc[i][j] + bf2f(xp[j]) * Dvv);
  }
}

// ---------------- gating + RMSNorm (in-place within zx buffer) ----------------
__global__ __launch_bounds__(256) void gatenorm_k(u16* __restrict__ zx,
                                                  const float* __restrict__ nwf) {
  const int row = blockIdx.x;
  const int tid = threadIdx.x;
  u16* zrow = zx + (size_t)row * D_IN_PROJ;
  u16* yrow = zrow + D_INNER;
  float vals[16];
  float ss = 0.f;
  #pragma unroll
  for (int q = 0; q < 16; ++q) {
    int e = tid + q * 256;
    float yv = bf2f(yrow[e]);
    float zv = bf2f(zrow[e]);
    float g = yv * (zv / (1.f + __expf(-zv)));
    vals[q] = g;
    ss += g * g;
  }
  #pragma unroll
  for (int off = 1; off < 64; off <<= 1) ss += __shfl_xor(ss, off);
  __shared__ float red[4];
  int lane = tid & 63, wv = tid >> 6;
  if (lane == 0) red[wv] = ss;
  __syncthreads();
  float tot = red[0] + red[1] + red[2] + red[3];
  float scale = rsqrtf(tot * (1.f / D_INNER) + EPS_F);
  #pragma unroll
  for (int q = 0; q < 16; ++q) {
    int e = tid + q * 256;
    yrow[e] = f2bf(vals[q] * scale * nwf[e]);
  }
}

extern "C" void kernel_launch(void* const* d_in, const int* in_sizes, int n_in,
                              void* d_out, int out_size, void* d_ws, size_t ws_size,
                              hipStream_t stream) {
  (void)in_sizes; (void)n_in; (void)out_size; (void)ws_size;
  const void* u       = d_in[0];
  const void* W_in    = d_in[1];
  const void* conv_w  = d_in[2];
  const void* conv_b  = d_in[3];
  const void* dt_bias = d_in[4];
  const void* A_log   = d_in[5];
  const void* Dv      = d_in[6];
  const void* norm_w  = d_in[7];
  const void* W_out   = d_in[8];

  const long N_U    = (long)ROWS * D_MODEL;        // 16,777,216
  const long N_WIN  = (long)D_IN_PROJ * D_MODEL;   // 17,104,896
  const long N_WINP = (long)NPAD * D_MODEL;        // 17,301,504
  const long N_WOUT = (long)D_MODEL * D_INNER;     // 8,388,608

  char* w = (char*)d_ws;
  size_t o = 0;
  int*   flag  = (int*)(w + o);    o += 256;
  float* smallp= (float*)(w + o);  o += ((size_t)N_SMALL * 4 + 255) & ~(size_t)255;
  u16* zx      = (u16*)(w + o);    o += (size_t)ROWS * D_IN_PROJ * 2;          // 136.8 MB
  // R2: Win_b (step1) -> xbc (steps 2..7) -> Wout_b (step 7.5..9)
  u16* r2      = (u16*)(w + o);    o += (size_t)ROWS * CONV_DIM * 2;           // 69.2 MB
  // R3: u_b (step1) -> states (steps 4..7)   (both exactly 33,554,432 B)
  char* r3     = (char*)(w + o);   o += (size_t)BATCH * NC * NHEADS * D_HEAD * D_STATE * 4;
  float* dtf   = (float*)(w + o);  o += (size_t)ROWS * NHEADS * 4;             // 1.0 MB
  float* cumf  = (float*)(w + o);  o += (size_t)BATCH * NC * NHEADS * CHUNK * 4; // 1.0 MB
  float* cdec  = (float*)(w + o);  o += ((size_t)BATCH * NC * NHEADS * 4 + 255) & ~(size_t)255;
  float* scores= (float*)(w + o);  o += (size_t)BATCH * NC * CHUNK * CHUNK * 4;  // 8.4 MB
  // total ~250 MB

  u16* Win_b  = r2;
  u16* xbc    = r2;
  u16* Wout_b = r2;
  u16* u_b    = (u16*)r3;
  float* states = (float*)r3;

  float* cwf  = smallp;
  float* cbf  = smallp + N_CW;
  float* dtbf = cbf + N_CB;
  float* alogf= dtbf + 32;
  float* df   = alogf + 32;
  float* nwf  = df + 32;

  // 0. dtype detect + conversions
  detect_k<<<1, 256, 0, stream>>>((const u16*)W_in, flag);
  convert_small_k<<<(N_SMALL + 255) / 256, 256, 0, stream>>>(
      conv_w, conv_b, dt_bias, A_log, Dv, norm_w, flag, smallp);
  to_bf16_k<<<(int)((N_U / 8 + 255) / 256), 256, 0, stream>>>(u, u_b, N_U, N_U, flag);
  to_bf16_k<<<(int)((N_WINP / 8 + 255) / 256), 256, 0, stream>>>(W_in, Win_b, N_WIN, N_WINP, flag);

  // 1. in_proj: zx[8192,8352] = u_b @ Win_b^T
  gemm_mfma<0><<<dim3(NPAD / 128, ROWS / 128), 256, 0, stream>>>(
      u_b, D_MODEL, Win_b, zx, D_IN_PROJ, ROWS, D_IN_PROJ, D_MODEL, flag);
  // 2. conv + silu
  conv_silu_k<<<dim3((CONV_DIM + 255) / 256, ROWS), 256, 0, stream>>>(zx, cwf, cbf, xbc);
  // 3. dt softplus
  dt_softplus_k<<<dim3(ROWS * NHEADS / 256), 256, 0, stream>>>(zx, dtbf, dtf);
  // 4. chunk states
  chunk_states_k<<<dim3(NHEADS, NC, BATCH), 256, 0, stream>>>(xbc, dtf, alogf, cumf, cdec, states);
  // 5. scan (in-place)
  scan_k<<<dim3(NHEADS, BATCH), 256, 0, stream>>>(states, cdec);
  // 6. scores
  scores_k<<<dim3(16, NC, BATCH), 256, 0, stream>>>(xbc, scores);
  // 7. Y (into zx dead cols [4096,8192))
  ydiag_off_k<<<dim3(NHEADS * 2, NC, BATCH), 256, 0, stream>>>(
      xbc, dtf, cumf, scores, states, df, zx);
  // 7.5 convert W_out into R2 (xbc dead now)
  to_bf16_k<<<(int)((N_WOUT / 8 + 255) / 256), 256, 0, stream>>>(W_out, Wout_b, N_WOUT, N_WOUT, flag);
  // 8. gate + norm (in-place)
  gatenorm_k<<<dim3(ROWS), 256, 0, stream>>>(zx, nwf);
  // 9. out_proj: out[8192,2048] = yn @ Wout_b^T  (store dtype per flag)
  gemm_mfma<1><<<dim3(D_MODEL / 128, ROWS / 128), 256, 0, stream>>>(
      zx + D_INNER, D_IN_PROJ, Wout_b, d_out, D_MODEL, ROWS, D_MODEL, D_INNER, flag);
}